// Round 1
// baseline (63570.673 us; speedup 1.0000x reference)
//
#include <hip/hip_runtime.h>
#include <hip/hip_cooperative_groups.h>

namespace cg = cooperative_groups;

// Problem dims
#define B_Q 128
#define T_Q 1024
#define I_Q 256
#define H_Q 512

// Partition: 4 groups x 32 batch; 64 slices/group x 8 h-cols; 256 WGs x 256 thr
#define NGROUPS 4
#define BG      32
#define NSLICES 64
#define JW      8
#define NWG     (NGROUPS * NSLICES)
#define NTHR    256

// LDS: W tile 24 rows x (512 hh | 256 ih | 4 pad), h tile 32 x (512 | 4 pad)
// strides %32 == 4 -> bank spread 4b+k, conflict-free for 8-row x 8-dup waves
#define WROWS 24
#define WSTR  772
#define HSTR  516
#define LDS_FLOATS (WROWS * WSTR + BG * HSTR)   // 35040
#define LDS_BYTES  (LDS_FLOATS * 4)             // 140160 < 160 KiB

extern "C" __global__ void __launch_bounds__(NTHR, 1)
gru_scan_kernel(const float* __restrict__ x,
                const float* __restrict__ h0,
                const float* __restrict__ Wih,
                const float* __restrict__ bih,
                const float* __restrict__ Whh,
                const float* __restrict__ bhh,
                float* __restrict__ out)
{
    extern __shared__ float lds[];
    float* Wt = lds;                  // [WROWS][WSTR]
    float* Ht = lds + WROWS * WSTR;   // [BG][HSTR]

    // scratch carved from d_out (2 MB; we use 528 KB); final grid.sync()
    // precedes the epilogue overwrite, so no lifetime overlap.
    int*   flags = (int*)out;         // [NWG]
    float* hbuf  = out + 1024;        // [NGROUPS][2][BG][H_Q]

    const int wg  = blockIdx.x;
    const int g   = wg & (NGROUPS - 1);   // group: blockIdx%4 -> XCDs {g, g+4}
    const int s   = wg >> 2;              // slice 0..63
    const int tid = threadIdx.x;
    const int b   = tid >> 3;             // 0..31 local batch
    const int j   = tid & 7;              // 0..7 local h-col
    const int jg  = s * JW + j;           // global h-col 0..511
    const int bg  = g * BG + b;           // global batch row

    // ---- stage W slice: rows (gate*JW + jl) = [W_hh row | W_ih row]
    for (int idx = tid; idx < WROWS * 768; idx += NTHR) {
        int row  = idx / 768;
        int k    = idx - row * 768;
        int gate = row >> 3;
        int jl   = row & 7;
        int rowg = gate * H_Q + s * JW + jl;
        float v = (k < H_Q) ? Whh[(size_t)rowg * H_Q + k]
                            : Wih[(size_t)rowg * I_Q + (k - H_Q)];
        Wt[row * WSTR + k] = v;
    }

    const float bir = bih[jg],           bhr = bhh[jg];
    const float biz = bih[H_Q + jg],     bhz = bhh[H_Q + jg];
    const float bin = bih[2 * H_Q + jg], bhn = bhh[2 * H_Q + jg];

    if (tid == 0) flags[wg] = 0;
    cg::this_grid().sync();   // flags visible device-wide; also covers Wt (block barrier)

    const float* wr   = Wt + (0 * JW + j) * WSTR;
    const float* wz   = Wt + (1 * JW + j) * WSTR;
    const float* wn   = Wt + (2 * JW + j) * WSTR;
    const float* hrow = Ht + b * HSTR;
    const float* xrow = x + (size_t)bg * T_Q * I_Q;

    float lr = 0.f, lz = 0.f, ln = 0.f, lh = 0.f;

    for (int t = 1; t <= T_Q; ++t) {
        // ---- x-part dots first: independent of h(t-1), off the critical chain
        float4 xr4 = {0,0,0,0}, xz4 = {0,0,0,0}, xn4 = {0,0,0,0};
        const float* xp = xrow + (size_t)(t - 1) * I_Q;
        #pragma unroll 8
        for (int k = 0; k < I_Q; k += 4) {
            float4 xv  = *(const float4*)(xp + k);
            float4 wrv = *(const float4*)(wr + H_Q + k);
            float4 wzv = *(const float4*)(wz + H_Q + k);
            float4 wnv = *(const float4*)(wn + H_Q + k);
            xr4.x += xv.x * wrv.x; xr4.y += xv.y * wrv.y; xr4.z += xv.z * wrv.z; xr4.w += xv.w * wrv.w;
            xz4.x += xv.x * wzv.x; xz4.y += xv.y * wzv.y; xz4.z += xv.z * wzv.z; xz4.w += xv.w * wzv.w;
            xn4.x += xv.x * wnv.x; xn4.y += xv.y * wnv.y; xn4.z += xv.z * wnv.z; xn4.w += xv.w * wnv.w;
        }

        // ---- acquire h(t-1) into LDS
        if (t == 1) {
            for (int idx = tid; idx < BG * (H_Q / 4); idx += NTHR) {
                int bb = idx >> 7;
                int k4 = (idx & 127) << 2;
                float4 v = *(const float4*)(h0 + (size_t)(g * BG + bb) * H_Q + k4);
                *(float4*)(Ht + bb * HSTR + k4) = v;
            }
        } else {
            if (tid < NSLICES) {
                int widx = g + (tid << 2);   // all WGs of this group
                int cnt = 0;
                while (__hip_atomic_load(flags + widx, __ATOMIC_RELAXED,
                                         __HIP_MEMORY_SCOPE_AGENT) < t - 1) {
                    __builtin_amdgcn_s_sleep(2);
                    if (++cnt > 200000000) break;   // hang guard -> visible absmax fail
                }
            }
            __syncthreads();
            __threadfence();   // agent acquire: invalidate caches before h reads
            const float* src = hbuf + (size_t)(g * 2 + ((t - 1) & 1)) * (BG * H_Q);
            for (int idx = tid; idx < BG * (H_Q / 4); idx += NTHR) {
                int bb = idx >> 7;
                int k4 = (idx & 127) << 2;
                float4 v = *(const float4*)(src + bb * H_Q + k4);
                *(float4*)(Ht + bb * HSTR + k4) = v;
            }
        }
        __syncthreads();

        // ---- h-part dots from LDS (12 independent FMA chains -> no latency stalls)
        float4 ar = {0,0,0,0}, az = {0,0,0,0}, an = {0,0,0,0};
        #pragma unroll 8
        for (int k = 0; k < H_Q; k += 4) {
            float4 hv  = *(const float4*)(hrow + k);
            float4 wrv = *(const float4*)(wr + k);
            float4 wzv = *(const float4*)(wz + k);
            float4 wnv = *(const float4*)(wn + k);
            ar.x += hv.x * wrv.x; ar.y += hv.y * wrv.y; ar.z += hv.z * wrv.z; ar.w += hv.w * wrv.w;
            az.x += hv.x * wzv.x; az.y += hv.y * wzv.y; az.z += hv.z * wzv.z; az.w += hv.w * wzv.w;
            an.x += hv.x * wnv.x; an.y += hv.y * wnv.y; an.z += hv.z * wnv.z; an.w += hv.w * wnv.w;
        }

        float sr  = (ar.x + ar.y) + (ar.z + ar.w);
        float sz  = (az.x + az.y) + (az.z + az.w);
        float sn  = (an.x + an.y) + (an.z + an.w);
        float sxr = (xr4.x + xr4.y) + (xr4.z + xr4.w);
        float sxz = (xz4.x + xz4.y) + (xz4.z + xz4.w);
        float sxn = (xn4.x + xn4.y) + (xn4.z + xn4.w);

        float hx = hrow[jg];
        float rg = 1.f / (1.f + expf(-(sxr + bir + sr + bhr)));
        float zg = 1.f / (1.f + expf(-(sxz + biz + sz + bhz)));
        float ng = tanhf(sxn + bin + rg * (sn + bhn));
        float hn = (1.f - zg) * ng + zg * hx;

        // ---- publish h(t) slice
        float* dst = hbuf + (size_t)(g * 2 + (t & 1)) * (BG * H_Q);
        dst[b * H_Q + jg] = hn;
        __threadfence();          // agent release: drain slice to coherent point
        __syncthreads();
        if (tid == 0)
            __hip_atomic_store(flags + wg, t, __ATOMIC_RELEASE, __HIP_MEMORY_SCOPE_AGENT);

        lr = rg; lz = zg; ln = ng; lh = hn;
    }

    // everyone done reading scratch before we overwrite d_out
    cg::this_grid().sync();

    size_t o = (size_t)bg * (4 * H_Q);
    out[o + jg]             = lr;
    out[o + H_Q + jg]       = lz;
    out[o + 2 * H_Q + jg]   = ln;
    out[o + 3 * H_Q + jg]   = lh;
    size_t o2 = o + (size_t)B_Q * (4 * H_Q);
    out[o2 + jg]            = lr;
    out[o2 + H_Q + jg]      = lz;
    out[o2 + 2 * H_Q + jg]  = ln;
    out[o2 + 3 * H_Q + jg]  = lh;
}

extern "C" void kernel_launch(void* const* d_in, const int* in_sizes, int n_in,
                              void* d_out, int out_size, void* d_ws, size_t ws_size,
                              hipStream_t stream) {
    const float* x   = (const float*)d_in[0];
    const float* h0  = (const float*)d_in[1];
    const float* Wih = (const float*)d_in[2];
    const float* bih = (const float*)d_in[3];
    const float* Whh = (const float*)d_in[4];
    const float* bhh = (const float*)d_in[5];
    float* outp = (float*)d_out;

    (void)in_sizes; (void)n_in; (void)d_ws; (void)ws_size; (void)out_size;

    // opt in to >64 KB dynamic LDS (idempotent, host-side, capture-safe)
    hipFuncSetAttribute((const void*)gru_scan_kernel,
                        hipFuncAttributeMaxDynamicSharedMemorySize, LDS_BYTES);

    void* args[] = {(void*)&x, (void*)&h0, (void*)&Wih, (void*)&bih,
                    (void*)&Whh, (void*)&bhh, (void*)&outp};
    hipLaunchCooperativeKernel((const void*)gru_scan_kernel,
                               dim3(NWG), dim3(NTHR), args, LDS_BYTES, stream);
}

// Round 2
// 24727.968 us; speedup vs baseline: 2.5708x; 2.5708x over previous
//
#include <hip/hip_runtime.h>
#include <hip/hip_cooperative_groups.h>

namespace cg = cooperative_groups;

// Problem dims
#define B_Q 128
#define T_Q 1024
#define I_Q 256
#define H_Q 512

// Partition: 4 groups x 32 batch; 64 slices/group x 8 h-cols; 256 WGs x 256 thr
#define NGROUPS 4
#define BG      32
#define NSLICES 64
#define JW      8
#define NWG     (NGROUPS * NSLICES)
#define NTHR    256

// LDS: W tile 24 rows x (512 hh | 256 ih | 4 pad), h tile 32 x (512 | 4 pad)
#define WROWS 24
#define WSTR  772
#define HSTR  516
#define LDS_FLOATS (WROWS * WSTR + BG * HSTR)   // 35040
#define LDS_BYTES  (LDS_FLOATS * 4)             // 140160 < 160 KiB

extern "C" __global__ void __launch_bounds__(NTHR, 1)
gru_scan_kernel(const float* __restrict__ x,
                const float* __restrict__ h0,
                const float* __restrict__ Wih,
                const float* __restrict__ bih,
                const float* __restrict__ Whh,
                const float* __restrict__ bhh,
                float* __restrict__ out)
{
    extern __shared__ float lds[];
    float* Wt = lds;                  // [WROWS][WSTR]
    float* Ht = lds + WROWS * WSTR;   // [BG][HSTR]

    // scratch carved from d_out (2 MB; we use ~528 KB); final grid.sync()
    // precedes the epilogue overwrite, so no lifetime overlap.
    int*   flags = (int*)out;         // [NWG]
    float* hbuf  = out + 1024;        // [NGROUPS][2][BG][H_Q]

    const int wg  = blockIdx.x;
    const int g   = wg & (NGROUPS - 1);   // group -> XCDs {g, g+4}
    const int s   = wg >> 2;              // slice 0..63
    const int tid = threadIdx.x;
    const int b   = tid >> 3;             // 0..31 local batch
    const int j   = tid & 7;              // 0..7 local h-col
    const int jg  = s * JW + j;           // global h-col
    const int bg  = g * BG + b;           // global batch row

    // ---- stage W slice: rows (gate*JW + jl) = [W_hh row | W_ih row]
    for (int idx = tid; idx < WROWS * 768; idx += NTHR) {
        int row  = idx / 768;
        int k    = idx - row * 768;
        int gate = row >> 3;
        int jl   = row & 7;
        int rowg = gate * H_Q + s * JW + jl;
        float v = (k < H_Q) ? Whh[(size_t)rowg * H_Q + k]
                            : Wih[(size_t)rowg * I_Q + (k - H_Q)];
        Wt[row * WSTR + k] = v;
    }

    const float bir = bih[jg],           bhr = bhh[jg];
    const float biz = bih[H_Q + jg],     bhz = bhh[H_Q + jg];
    const float bin = bih[2 * H_Q + jg], bhn = bhh[2 * H_Q + jg];

    if (tid == 0)
        __hip_atomic_store(flags + wg, 0, __ATOMIC_RELAXED, __HIP_MEMORY_SCOPE_AGENT);
    cg::this_grid().sync();   // flags visible device-wide; also covers Wt

    const float* wr   = Wt + (0 * JW + j) * WSTR;
    const float* wz   = Wt + (1 * JW + j) * WSTR;
    const float* wn   = Wt + (2 * JW + j) * WSTR;
    const float* hrow = Ht + b * HSTR;
    const float* xrow = x + (size_t)bg * T_Q * I_Q;

    float lr = 0.f, lz = 0.f, ln = 0.f, lh = 0.f;

    for (int t = 1; t <= T_Q; ++t) {
        // ---- x-part dots first: independent of h(t-1), off the critical chain
        float4 xr4 = {0,0,0,0}, xz4 = {0,0,0,0}, xn4 = {0,0,0,0};
        const float* xp = xrow + (size_t)(t - 1) * I_Q;
        #pragma unroll 8
        for (int k = 0; k < I_Q; k += 4) {
            float4 xv  = *(const float4*)(xp + k);
            float4 wrv = *(const float4*)(wr + H_Q + k);
            float4 wzv = *(const float4*)(wz + H_Q + k);
            float4 wnv = *(const float4*)(wn + H_Q + k);
            xr4.x += xv.x * wrv.x; xr4.y += xv.y * wrv.y; xr4.z += xv.z * wrv.z; xr4.w += xv.w * wrv.w;
            xz4.x += xv.x * wzv.x; xz4.y += xv.y * wzv.y; xz4.z += xv.z * wzv.z; xz4.w += xv.w * wzv.w;
            xn4.x += xv.x * wnv.x; xn4.y += xv.y * wnv.y; xn4.z += xv.z * wnv.z; xn4.w += xv.w * wnv.w;
        }

        // ---- acquire h(t-1) into LDS
        if (t == 1) {
            for (int idx = tid; idx < BG * (H_Q / 4); idx += NTHR) {
                int bb = idx >> 7;
                int k4 = (idx & 127) << 2;
                float4 v = *(const float4*)(h0 + (size_t)(g * BG + bb) * H_Q + k4);
                *(float4*)(Ht + bb * HSTR + k4) = v;
            }
        } else {
            if (tid < NSLICES) {
                int widx = g + (tid << 2);   // all WGs of this group
                int cnt = 0;
                while (__hip_atomic_load(flags + widx, __ATOMIC_RELAXED,
                                         __HIP_MEMORY_SCOPE_AGENT) < t - 1) {
                    __builtin_amdgcn_s_sleep(2);
                    if (++cnt > 100000000) break;   // hang guard -> visible absmax fail
                }
            }
            __syncthreads();
            // MALL-coherent staging: agent-scope relaxed 64-bit loads read the
            // device-coherent point directly -> NO buffer_inv / threadfence needed.
            const unsigned long long* src2 = (const unsigned long long*)
                (hbuf + (size_t)(g * 2 + ((t - 1) & 1)) * (BG * H_Q));
            for (int idx = tid; idx < BG * (H_Q / 2); idx += NTHR) {   // 8192
                int bb = idx >> 8;             // / 256
                int k2 = (idx & 255) << 1;     // even float index
                unsigned long long v = __hip_atomic_load(src2 + (idx >> 8) * (H_Q / 2) + (idx & 255),
                                                         __ATOMIC_RELAXED,
                                                         __HIP_MEMORY_SCOPE_AGENT);
                *(unsigned long long*)(Ht + bb * HSTR + k2) = v;   // 2-way LDS alias: free
            }
        }
        __syncthreads();

        // ---- h-part dots from LDS
        float4 ar = {0,0,0,0}, az = {0,0,0,0}, an = {0,0,0,0};
        #pragma unroll 8
        for (int k = 0; k < H_Q; k += 4) {
            float4 hv  = *(const float4*)(hrow + k);
            float4 wrv = *(const float4*)(wr + k);
            float4 wzv = *(const float4*)(wz + k);
            float4 wnv = *(const float4*)(wn + k);
            ar.x += hv.x * wrv.x; ar.y += hv.y * wrv.y; ar.z += hv.z * wrv.z; ar.w += hv.w * wrv.w;
            az.x += hv.x * wzv.x; az.y += hv.y * wzv.y; az.z += hv.z * wzv.z; az.w += hv.w * wzv.w;
            an.x += hv.x * wnv.x; an.y += hv.y * wnv.y; an.z += hv.z * wnv.z; an.w += hv.w * wnv.w;
        }

        float sr  = (ar.x + ar.y) + (ar.z + ar.w);
        float sz  = (az.x + az.y) + (az.z + az.w);
        float sn  = (an.x + an.y) + (an.z + an.w);
        float sxr = (xr4.x + xr4.y) + (xr4.z + xr4.w);
        float sxz = (xz4.x + xz4.y) + (xz4.z + xz4.w);
        float sxn = (xn4.x + xn4.y) + (xn4.z + xn4.w);

        float hx = hrow[jg];
        float rg = 1.f / (1.f + expf(-(sxr + bir + sr + bhr)));
        float zg = 1.f / (1.f + expf(-(sxz + biz + sz + bhz)));
        float ng = tanhf(sxn + bin + rg * (sn + bhn));
        float hn = (1.f - zg) * ng + zg * hx;

        // ---- publish h(t) slice: write-through to MALL (sc1), no wbl2 fence
        float* dst = hbuf + (size_t)(g * 2 + (t & 1)) * (BG * H_Q);
        __hip_atomic_store(dst + b * H_Q + jg, hn,
                           __ATOMIC_RELAXED, __HIP_MEMORY_SCOPE_AGENT);
        // order: this wave's store reaches the coherent point before the flag
        asm volatile("s_waitcnt vmcnt(0)" ::: "memory");
        __syncthreads();
        if (tid == 0)
            __hip_atomic_store(flags + wg, t, __ATOMIC_RELAXED, __HIP_MEMORY_SCOPE_AGENT);

        lr = rg; lz = zg; ln = ng; lh = hn;
    }

    // everyone done reading scratch before we overwrite d_out
    cg::this_grid().sync();

    size_t o = (size_t)bg * (4 * H_Q);
    out[o + jg]             = lr;
    out[o + H_Q + jg]       = lz;
    out[o + 2 * H_Q + jg]   = ln;
    out[o + 3 * H_Q + jg]   = lh;
    size_t o2 = o + (size_t)B_Q * (4 * H_Q);
    out[o2 + jg]            = lr;
    out[o2 + H_Q + jg]      = lz;
    out[o2 + 2 * H_Q + jg]  = ln;
    out[o2 + 3 * H_Q + jg]  = lh;
}

extern "C" void kernel_launch(void* const* d_in, const int* in_sizes, int n_in,
                              void* d_out, int out_size, void* d_ws, size_t ws_size,
                              hipStream_t stream) {
    const float* x   = (const float*)d_in[0];
    const float* h0  = (const float*)d_in[1];
    const float* Wih = (const float*)d_in[2];
    const float* bih = (const float*)d_in[3];
    const float* Whh = (const float*)d_in[4];
    const float* bhh = (const float*)d_in[5];
    float* outp = (float*)d_out;

    (void)in_sizes; (void)n_in; (void)d_ws; (void)ws_size; (void)out_size;

    hipFuncSetAttribute((const void*)gru_scan_kernel,
                        hipFuncAttributeMaxDynamicSharedMemorySize, LDS_BYTES);

    void* args[] = {(void*)&x, (void*)&h0, (void*)&Wih, (void*)&bih,
                    (void*)&Whh, (void*)&bhh, (void*)&outp};
    hipLaunchCooperativeKernel((const void*)gru_scan_kernel,
                               dim3(NWG), dim3(NTHR), args, LDS_BYTES, stream);
}

// Round 6
// 18273.294 us; speedup vs baseline: 3.4789x; 1.3532x over previous
//
#include <hip/hip_runtime.h>

typedef float v2f __attribute__((ext_vector_type(2)));

// Problem dims
#define B_Q 128
#define T_Q 1024
#define I_Q 256
#define H_Q 512

// Partition: 4 groups x 32 batch; 64 slices/group x 8 h-cols; 256 WGs x 256 thr
// Thread = (j 0..7, kg 0..31): col jg = s*8+j, k-slice (16 hh + 8 ih) in VGPRs
#define BG      32
#define JW      8
#define NWG     256
#define NTHR    256

// LDS: h tile, chunked: 32 rows x 64 chunks x (8 floats + 2 pad)
// chunk stride 10 -> lanes kg / kg+16 alias 2-way on b64 reads = free (m136)
#define CH_STR  10
#define ROW_STR 640                      // 64 * 10
#define LDS_FLOATS (BG * ROW_STR)        // 20480
#define LDS_BYTES  (LDS_FLOATS * 4)      // 81920 (needs >64KB opt-in attr)

// ---- cross-lane partner fetch, compile-time ctrl (DPP for 1,2,8; swizzle 4,16)
template<int M>
__device__ __forceinline__ float partner(float t) {
    if constexpr (M == 16)
        return __int_as_float(__builtin_amdgcn_ds_swizzle(__float_as_int(t), 0x401F));
    else if constexpr (M == 8)
        return __int_as_float(__builtin_amdgcn_update_dpp(0, __float_as_int(t), 0x128, 0xF, 0xF, true)); // row_ror:8 = xor8
    else if constexpr (M == 4)
        return __int_as_float(__builtin_amdgcn_ds_swizzle(__float_as_int(t), 0x101F));
    else if constexpr (M == 2)
        return __int_as_float(__builtin_amdgcn_update_dpp(0, __float_as_int(t), 0x4E, 0xF, 0xF, true));  // quad_perm [2,3,0,1]
    else
        return __int_as_float(__builtin_amdgcn_update_dpp(0, __float_as_int(t), 0xB1, 0xF, 0xF, true));  // quad_perm [1,0,3,2]
}

// reduce-scatter stage: keep the half matching our bit, send the other half;
// partner's send is exactly the partial for the batch we keep.
template<int M, int N>
__device__ __forceinline__ void bstage(float* v, bool hi) {
    #pragma unroll
    for (int i = 0; i < N / 2; ++i) {
        float keep = hi ? v[i + N / 2] : v[i];
        float send = hi ? v[i]         : v[i + N / 2];
        v[i] = keep + partner<M>(send);
    }
}

// chunk=16 butterfly: v[i] = partial for batch base+i. Stage 1 folds ^16
// symmetrically (both lanes of a pair compute the same sum -> no select),
// stages ^8..^1 reduce-scatter across the 16-lane row.
// After: EVERY lane kg has v[0] = full 32-lane sum for batch base + (kg&15).
__device__ __forceinline__ void bflychunk(float* v, int kg) {
    #pragma unroll
    for (int i = 0; i < 16; ++i) v[i] += partner<16>(v[i]);
    bstage<8, 16>(v, (kg & 8) != 0);
    bstage<4, 8 >(v, (kg & 4) != 0);
    bstage<2, 4 >(v, (kg & 2) != 0);
    bstage<1, 2 >(v, (kg & 1) != 0);
}

extern "C" __global__ void __launch_bounds__(NTHR, 1)
gru_scan_kernel(const float* __restrict__ x,
                const float* __restrict__ h0,
                const float* __restrict__ Wih,
                const float* __restrict__ bih,
                const float* __restrict__ Whh,
                const float* __restrict__ bhh,
                float* __restrict__ out,
                int* __restrict__ flags)   // d_ws: 256 ints, start as poison (<1)
{
    extern __shared__ float Ht[];     // h(t-1) tile, chunked layout

    // hbuf scratch carved from out[1024..132096); every hbuf READ completes
    // before any WG passes the final all-done spin, so the epilogue overwrite
    // is safe. flags live in d_ws so epilogue float-bit writes never alias them.
    float* hbuf = out + 1024;         // [4 groups][2 parity][BG][H_Q]

    const int wg  = blockIdx.x;
    const int g   = wg & 3;               // group -> XCDs {g, g+4}
    const int s   = wg >> 2;              // slice 0..63
    const int tid = threadIdx.x;
    const int j   = tid >> 5;             // 0..7 local col
    const int kg  = tid & 31;             // 0..31 k-group (lane in half-wave)
    const int jg  = s * JW + j;           // global h-col

    // ---- W slices into registers (v2f for packed fp32 fma)
    v2f wh[3][8];   // hh: k in [8kg,8kg+8) U [256+8kg, 256+8kg+8)
    v2f wi[3][4];   // ih: k in [8kg,8kg+8)
    #pragma unroll
    for (int gt = 0; gt < 3; ++gt) {
        const float* wr = Whh + (size_t)(gt * H_Q + jg) * H_Q + 8 * kg;
        float4 t0 = *(const float4*)(wr);
        float4 t1 = *(const float4*)(wr + 4);
        float4 t2 = *(const float4*)(wr + 256);
        float4 t3 = *(const float4*)(wr + 260);
        wh[gt][0] = (v2f){t0.x, t0.y}; wh[gt][1] = (v2f){t0.z, t0.w};
        wh[gt][2] = (v2f){t1.x, t1.y}; wh[gt][3] = (v2f){t1.z, t1.w};
        wh[gt][4] = (v2f){t2.x, t2.y}; wh[gt][5] = (v2f){t2.z, t2.w};
        wh[gt][6] = (v2f){t3.x, t3.y}; wh[gt][7] = (v2f){t3.z, t3.w};
        const float* wx = Wih + (size_t)(gt * H_Q + jg) * I_Q + 8 * kg;
        float4 u0 = *(const float4*)(wx);
        float4 u1 = *(const float4*)(wx + 4);
        wi[gt][0] = (v2f){u0.x, u0.y}; wi[gt][1] = (v2f){u0.z, u0.w};
        wi[gt][2] = (v2f){u1.x, u1.y}; wi[gt][3] = (v2f){u1.z, u1.w};
    }

    const float br = bih[jg]           + bhh[jg];
    const float bz = bih[H_Q + jg]     + bhh[H_Q + jg];
    const float bin = bih[2 * H_Q + jg], bhn = bhh[2 * H_Q + jg];

    const size_t xstr_b = (size_t)T_Q * I_Q;
    const float* xbase  = x + (size_t)(g * BG) * xstr_b + 8 * kg;

    float lr = 0.f, lz = 0.f, ln = 0.f, lh = 0.f;

    for (int t = 1; t <= T_Q; ++t) {
        // ---- phase 1: x own-sums (independent of h(t-1), off critical chain)
        float oxr = 0.f, oxz = 0.f, oxn = 0.f;
        const float* xt = xbase + (size_t)(t - 1) * I_Q;
        #pragma unroll 1
        for (int c = 0; c < 2; ++c) {
            float pr[16], pz[16], pn[16];
            #pragma unroll
            for (int i = 0; i < 16; ++i) {
                const float* xp = xt + (size_t)(16 * c + i) * xstr_b;
                float4 xa4 = *(const float4*)(xp);
                float4 xb4 = *(const float4*)(xp + 4);
                v2f x0 = (v2f){xa4.x, xa4.y}, x1 = (v2f){xa4.z, xa4.w};
                v2f x2 = (v2f){xb4.x, xb4.y}, x3 = (v2f){xb4.z, xb4.w};
                v2f sr = x0 * wi[0][0] + x1 * wi[0][1] + x2 * wi[0][2] + x3 * wi[0][3];
                v2f sz = x0 * wi[1][0] + x1 * wi[1][1] + x2 * wi[1][2] + x3 * wi[1][3];
                v2f sn = x0 * wi[2][0] + x1 * wi[2][1] + x2 * wi[2][2] + x3 * wi[2][3];
                pr[i] = sr.x + sr.y;
                pz[i] = sz.x + sz.y;
                pn[i] = sn.x + sn.y;
            }
            bflychunk(pr, kg); bflychunk(pz, kg); bflychunk(pn, kg);
            if ((kg >> 4) == c) { oxr = pr[0]; oxz = pz[0]; oxn = pn[0]; }
        }

        // ---- acquire h(t-1) into LDS (chunked layout)
        if (t == 1) {
            const unsigned long long* src =
                (const unsigned long long*)(h0 + (size_t)(g * BG) * H_Q);
            #pragma unroll 8
            for (int q = tid; q < BG * (H_Q / 2); q += NTHR) {
                int b = q >> 8, qr = q & 255;
                unsigned long long v = src[q];
                *(unsigned long long*)(Ht + b * ROW_STR + (qr >> 2) * CH_STR
                                       + ((qr & 3) << 1)) = v;
            }
        } else {
            if (tid < 64) {
                int widx = g + (tid << 2);   // all WGs of this group
                int cnt = 0;
                while (__hip_atomic_load(flags + widx, __ATOMIC_RELAXED,
                                         __HIP_MEMORY_SCOPE_AGENT) < t - 1) {
                    __builtin_amdgcn_s_sleep(2);
                    if (++cnt > 100000000) break;   // hang guard
                }
            }
            __syncthreads();
            const unsigned long long* src = (const unsigned long long*)
                (hbuf + (size_t)(g * 2 + ((t - 1) & 1)) * (BG * H_Q));
            #pragma unroll 8
            for (int q = tid; q < BG * (H_Q / 2); q += NTHR) {
                int b = q >> 8, qr = q & 255;
                unsigned long long v = __hip_atomic_load(src + q, __ATOMIC_RELAXED,
                                                         __HIP_MEMORY_SCOPE_AGENT);
                *(unsigned long long*)(Ht + b * ROW_STR + (qr >> 2) * CH_STR
                                       + ((qr & 3) << 1)) = v;
            }
        }
        __syncthreads();

        // ---- phase 2: h own-sums, same chunked structure
        float ohr = 0.f, ohz = 0.f, ohn = 0.f;
        #pragma unroll 1
        for (int c = 0; c < 2; ++c) {
            float pr[16], pz[16], pn[16];
            #pragma unroll
            for (int i = 0; i < 16; ++i) {
                const float* hp = Ht + (16 * c + i) * ROW_STR + CH_STR * kg;
                v2f a0 = *(const v2f*)(hp);
                v2f a1 = *(const v2f*)(hp + 2);
                v2f a2 = *(const v2f*)(hp + 4);
                v2f a3 = *(const v2f*)(hp + 6);
                const float* hq = hp + 32 * CH_STR;   // chunk kg+32: k=256+8kg
                v2f c0 = *(const v2f*)(hq);
                v2f c1 = *(const v2f*)(hq + 2);
                v2f c2 = *(const v2f*)(hq + 4);
                v2f c3 = *(const v2f*)(hq + 6);
                v2f sr = a0 * wh[0][0] + a1 * wh[0][1] + a2 * wh[0][2] + a3 * wh[0][3]
                       + c0 * wh[0][4] + c1 * wh[0][5] + c2 * wh[0][6] + c3 * wh[0][7];
                v2f sz = a0 * wh[1][0] + a1 * wh[1][1] + a2 * wh[1][2] + a3 * wh[1][3]
                       + c0 * wh[1][4] + c1 * wh[1][5] + c2 * wh[1][6] + c3 * wh[1][7];
                v2f sn = a0 * wh[2][0] + a1 * wh[2][1] + a2 * wh[2][2] + a3 * wh[2][3]
                       + c0 * wh[2][4] + c1 * wh[2][5] + c2 * wh[2][6] + c3 * wh[2][7];
                pr[i] = sr.x + sr.y;
                pz[i] = sz.x + sz.y;
                pn[i] = sn.x + sn.y;
            }
            bflychunk(pr, kg); bflychunk(pz, kg); bflychunk(pn, kg);
            if ((kg >> 4) == c) { ohr = pr[0]; ohz = pz[0]; ohn = pn[0]; }
        }

        // previous h for this thread's kept (b=kg, col jg)
        float hx = Ht[kg * ROW_STR + (jg >> 3) * CH_STR + (jg & 7)];

        float rg = 1.f / (1.f + expf(-(oxr + ohr + br)));
        float zg = 1.f / (1.f + expf(-(oxz + ohz + bz)));
        float ng = tanhf(oxn + bin + rg * (ohn + bhn));
        float hn = (1.f - zg) * ng + zg * hx;

        // ---- publish h(t): 256 unique (b=kg, col jg) values, device-coherent
        float* dst = hbuf + (size_t)(g * 2 + (t & 1)) * (BG * H_Q);
        __hip_atomic_store(dst + kg * H_Q + jg, hn,
                           __ATOMIC_RELAXED, __HIP_MEMORY_SCOPE_AGENT);
        asm volatile("s_waitcnt vmcnt(0)" ::: "memory");
        __syncthreads();
        if (tid == 0)
            __hip_atomic_store(flags + wg, t, __ATOMIC_RELAXED, __HIP_MEMORY_SCOPE_AGENT);

        lr = rg; lz = zg; ln = ng; lh = hn;
    }

    // ---- all-done barrier (replaces grid.sync): wait until every WG has
    // published step T, so no one still reads hbuf when we overwrite out.
    if (tid < NWG) {
        int cnt = 0;
        while (__hip_atomic_load(flags + tid, __ATOMIC_RELAXED,
                                 __HIP_MEMORY_SCOPE_AGENT) < T_Q) {
            __builtin_amdgcn_s_sleep(2);
            if (++cnt > 100000000) break;   // hang guard
        }
    }
    __syncthreads();

    size_t o = (size_t)(g * BG + kg) * (4 * H_Q);
    out[o + jg]             = lr;
    out[o + H_Q + jg]       = lz;
    out[o + 2 * H_Q + jg]   = ln;
    out[o + 3 * H_Q + jg]   = lh;
    size_t o2 = o + (size_t)B_Q * (4 * H_Q);
    out[o2 + jg]            = lr;
    out[o2 + H_Q + jg]      = lz;
    out[o2 + 2 * H_Q + jg]  = ln;
    out[o2 + 3 * H_Q + jg]  = lh;
}

extern "C" void kernel_launch(void* const* d_in, const int* in_sizes, int n_in,
                              void* d_out, int out_size, void* d_ws, size_t ws_size,
                              hipStream_t stream) {
    const float* x   = (const float*)d_in[0];
    const float* h0  = (const float*)d_in[1];
    const float* Wih = (const float*)d_in[2];
    const float* bih = (const float*)d_in[3];
    const float* Whh = (const float*)d_in[4];
    const float* bhh = (const float*)d_in[5];
    float* outp = (float*)d_out;
    int*   flags = (int*)d_ws;   // 1 KB; poison 0xAA (<1) is a valid init

    (void)in_sizes; (void)n_in; (void)ws_size; (void)out_size;

    (void)hipFuncSetAttribute((const void*)gru_scan_kernel,
                              hipFuncAttributeMaxDynamicSharedMemorySize, LDS_BYTES);

    gru_scan_kernel<<<dim3(NWG), dim3(NTHR), LDS_BYTES, stream>>>(
        x, h0, Wih, bih, Whh, bhh, outp, flags);
}

// Round 7
// 10255.090 us; speedup vs baseline: 6.1989x; 1.7819x over previous
//
#include <hip/hip_runtime.h>

typedef float v2f __attribute__((ext_vector_type(2)));

// Problem dims
#define B_Q 128
#define T_Q 1024
#define I_Q 256
#define H_Q 512

// Partition: 8 groups x 16 batch; 64 slices/group x 8 h-cols; 512 WGs x 256 thr
// 2 WGs/CU co-resident (different groups -> stall overlap).
// Thread = (j 0..7, kg 0..31): col jg = s*8+j, k-slice (16 hh + 8 ih) in VGPRs
#define NGR    8
#define BG     16
#define JW     8
#define NWG    512
#define NTHR   256

// LDS: h tile chunked: 16 rows x 64 chunks x (8 floats + 2 pad), + transpose buf
#define CH_STR  10
#define ROW_STR 640                      // 64 * 10
#define HT_FLOATS (BG * ROW_STR)         // 10240
#define TB_FLOATS (BG * 9)               // 144 (stride 9: conflict-free)
#define LDS_FLOATS (HT_FLOATS + TB_FLOATS)
#define LDS_BYTES  (LDS_FLOATS * 4)      // 41536 < 64KB -> 2 WGs/CU

// ---- cross-lane partner fetch, compile-time ctrl (DPP for 1,2,8; swizzle 4,16)
template<int M>
__device__ __forceinline__ float partner(float t) {
    if constexpr (M == 16)
        return __int_as_float(__builtin_amdgcn_ds_swizzle(__float_as_int(t), 0x401F));
    else if constexpr (M == 8)
        return __int_as_float(__builtin_amdgcn_update_dpp(0, __float_as_int(t), 0x128, 0xF, 0xF, true)); // row_ror:8 = xor8
    else if constexpr (M == 4)
        return __int_as_float(__builtin_amdgcn_ds_swizzle(__float_as_int(t), 0x101F));
    else if constexpr (M == 2)
        return __int_as_float(__builtin_amdgcn_update_dpp(0, __float_as_int(t), 0x4E, 0xF, 0xF, true));  // quad_perm [2,3,0,1]
    else
        return __int_as_float(__builtin_amdgcn_update_dpp(0, __float_as_int(t), 0xB1, 0xF, 0xF, true));  // quad_perm [1,0,3,2]
}

// reduce-scatter stage: keep the half matching our bit, send the other half
template<int M, int N>
__device__ __forceinline__ void bstage(float* v, bool hi) {
    #pragma unroll
    for (int i = 0; i < N / 2; ++i) {
        float keep = hi ? v[i + N / 2] : v[i];
        float send = hi ? v[i]         : v[i + N / 2];
        v[i] = keep + partner<M>(send);
    }
}

// 16-batch butterfly: fold ^16 symmetrically, then reduce-scatter ^8..^1.
// After: EVERY lane kg has v[0] = full 32-lane sum for batch (kg & 15).
__device__ __forceinline__ void bflychunk(float* v, int kg) {
    #pragma unroll
    for (int i = 0; i < 16; ++i) v[i] += partner<16>(v[i]);
    bstage<8, 16>(v, (kg & 8) != 0);
    bstage<4, 8 >(v, (kg & 4) != 0);
    bstage<2, 4 >(v, (kg & 2) != 0);
    bstage<1, 2 >(v, (kg & 1) != 0);
}

extern "C" __global__ void __launch_bounds__(NTHR, 2)
gru_scan_kernel(const float* __restrict__ x,
                const float* __restrict__ h0,
                const float* __restrict__ Wih,
                const float* __restrict__ bih,
                const float* __restrict__ Whh,
                const float* __restrict__ bhh,
                float* __restrict__ out,
                int* __restrict__ flags)   // d_ws: 512 ints; poison 0xAA < 1 ok
{
    extern __shared__ float lds[];
    float* Ht   = lds;                 // [BG][ROW_STR] chunked h(t-1)
    float* tbuf = lds + HT_FLOATS;     // [BG][9] publish transpose

    // hbuf scratch carved from out[1024 .. 1024+8*2*16*512); all hbuf reads
    // finish before any WG passes the final all-done spin -> epilogue safe.
    float* hbuf = out + 1024;          // [NGR][2 parity][BG][H_Q] natural layout

    const int wg  = blockIdx.x;
    const int g   = wg >> 6;              // group 0..7 (high bits: co-resident
    const int s   = wg & 63;              //   CU pairs land in different groups)
    const int tid = threadIdx.x;
    const int j   = tid >> 5;             // 0..7 local col
    const int kg  = tid & 31;             // 0..31 k-group
    const int jg  = s * JW + j;           // global h-col
    const int b_own = kg & 15;            // batch this thread's sums land on

    // ---- W slices into registers (v2f for packed fp32 fma)
    v2f wh[3][8];   // hh: k in [8kg,8kg+8) U [256+8kg, 256+8kg+8)
    v2f wi[3][4];   // ih: k in [8kg,8kg+8)
    #pragma unroll
    for (int gt = 0; gt < 3; ++gt) {
        const float* wr = Whh + (size_t)(gt * H_Q + jg) * H_Q + 8 * kg;
        float4 t0 = *(const float4*)(wr);
        float4 t1 = *(const float4*)(wr + 4);
        float4 t2 = *(const float4*)(wr + 256);
        float4 t3 = *(const float4*)(wr + 260);
        wh[gt][0] = (v2f){t0.x, t0.y}; wh[gt][1] = (v2f){t0.z, t0.w};
        wh[gt][2] = (v2f){t1.x, t1.y}; wh[gt][3] = (v2f){t1.z, t1.w};
        wh[gt][4] = (v2f){t2.x, t2.y}; wh[gt][5] = (v2f){t2.z, t2.w};
        wh[gt][6] = (v2f){t3.x, t3.y}; wh[gt][7] = (v2f){t3.z, t3.w};
        const float* wx = Wih + (size_t)(gt * H_Q + jg) * I_Q + 8 * kg;
        float4 u0 = *(const float4*)(wx);
        float4 u1 = *(const float4*)(wx + 4);
        wi[gt][0] = (v2f){u0.x, u0.y}; wi[gt][1] = (v2f){u0.z, u0.w};
        wi[gt][2] = (v2f){u1.x, u1.y}; wi[gt][3] = (v2f){u1.z, u1.w};
    }

    const float br = bih[jg]           + bhh[jg];
    const float bz = bih[H_Q + jg]     + bhh[H_Q + jg];
    const float bin = bih[2 * H_Q + jg], bhn = bhh[2 * H_Q + jg];

    const size_t xstr_b = (size_t)T_Q * I_Q;
    const float* xbase  = x + (size_t)(g * BG) * xstr_b + 8 * kg;

    float lr = 0.f, lz = 0.f, ln = 0.f, lh = 0.f;

    for (int t = 1; t <= T_Q; ++t) {
        // ---- phase 1: x partials (independent of h(t-1) -> overlaps stall)
        float pr[BG], pz[BG], pn[BG];
        const float* xt = xbase + (size_t)(t - 1) * I_Q;
        #pragma unroll
        for (int i = 0; i < BG; ++i) {
            const float* xp = xt + (size_t)i * xstr_b;
            float4 xa4 = *(const float4*)(xp);
            float4 xb4 = *(const float4*)(xp + 4);
            v2f x0 = (v2f){xa4.x, xa4.y}, x1 = (v2f){xa4.z, xa4.w};
            v2f x2 = (v2f){xb4.x, xb4.y}, x3 = (v2f){xb4.z, xb4.w};
            v2f sr = x0 * wi[0][0] + x1 * wi[0][1] + x2 * wi[0][2] + x3 * wi[0][3];
            v2f sz = x0 * wi[1][0] + x1 * wi[1][1] + x2 * wi[1][2] + x3 * wi[1][3];
            v2f sn = x0 * wi[2][0] + x1 * wi[2][1] + x2 * wi[2][2] + x3 * wi[2][3];
            pr[i] = sr.x + sr.y;
            pz[i] = sz.x + sz.y;
            pn[i] = sn.x + sn.y;
        }
        bflychunk(pr, kg); bflychunk(pz, kg); bflychunk(pn, kg);
        const float oxr = pr[0], oxz = pz[0], oxn = pn[0];

        // ---- acquire h(t-1) into LDS (contiguous global -> chunked LDS)
        if (t == 1) {
            const unsigned long long* src =
                (const unsigned long long*)(h0 + (size_t)(g * BG) * H_Q);
            #pragma unroll
            for (int i = 0; i < BG; ++i) {
                int q = tid + i * NTHR;            // 0..4095
                int b = q >> 8, qr = q & 255;
                unsigned long long v = src[q];
                *(unsigned long long*)(Ht + b * ROW_STR + (qr >> 2) * CH_STR
                                       + ((qr & 3) << 1)) = v;
            }
        } else {
            if (tid < 64) {
                int cnt = 0;
                while (__hip_atomic_load(flags + g * 64 + tid, __ATOMIC_RELAXED,
                                         __HIP_MEMORY_SCOPE_AGENT) < t - 1) {
                    __builtin_amdgcn_s_sleep(2);
                    if (++cnt > 100000000) break;   // hang guard
                }
            }
            __syncthreads();
            const unsigned long long* src = (const unsigned long long*)
                (hbuf + (size_t)(g * 2 + ((t - 1) & 1)) * (BG * H_Q));
            #pragma unroll
            for (int i = 0; i < BG; ++i) {
                int q = tid + i * NTHR;
                int b = q >> 8, qr = q & 255;
                unsigned long long v = __hip_atomic_load(src + q, __ATOMIC_RELAXED,
                                                         __HIP_MEMORY_SCOPE_AGENT);
                *(unsigned long long*)(Ht + b * ROW_STR + (qr >> 2) * CH_STR
                                       + ((qr & 3) << 1)) = v;
            }
        }
        __syncthreads();

        // ---- phase 2: h partials
        #pragma unroll
        for (int i = 0; i < BG; ++i) {
            const float* hp = Ht + i * ROW_STR + CH_STR * kg;
            v2f a0 = *(const v2f*)(hp);
            v2f a1 = *(const v2f*)(hp + 2);
            v2f a2 = *(const v2f*)(hp + 4);
            v2f a3 = *(const v2f*)(hp + 6);
            const float* hq = hp + 32 * CH_STR;   // chunk kg+32: k = 256+8kg
            v2f c0 = *(const v2f*)(hq);
            v2f c1 = *(const v2f*)(hq + 2);
            v2f c2 = *(const v2f*)(hq + 4);
            v2f c3 = *(const v2f*)(hq + 6);
            v2f sr = a0 * wh[0][0] + a1 * wh[0][1] + a2 * wh[0][2] + a3 * wh[0][3]
                   + c0 * wh[0][4] + c1 * wh[0][5] + c2 * wh[0][6] + c3 * wh[0][7];
            v2f sz = a0 * wh[1][0] + a1 * wh[1][1] + a2 * wh[1][2] + a3 * wh[1][3]
                   + c0 * wh[1][4] + c1 * wh[1][5] + c2 * wh[1][6] + c3 * wh[1][7];
            v2f sn = a0 * wh[2][0] + a1 * wh[2][1] + a2 * wh[2][2] + a3 * wh[2][3]
                   + c0 * wh[2][4] + c1 * wh[2][5] + c2 * wh[2][6] + c3 * wh[2][7];
            pr[i] = sr.x + sr.y;
            pz[i] = sz.x + sz.y;
            pn[i] = sn.x + sn.y;
        }
        bflychunk(pr, kg); bflychunk(pz, kg); bflychunk(pn, kg);

        // previous h for this thread's (b_own, col jg)
        float hx = Ht[b_own * ROW_STR + (jg >> 3) * CH_STR + (jg & 7)];

        float rg = 1.f / (1.f + expf(-(oxr + pr[0] + br)));
        float zg = 1.f / (1.f + expf(-(oxz + pz[0] + bz)));
        float ng = tanhf(oxn + bin + rg * (pn[0] + bhn));
        float hn = (1.f - zg) * ng + zg * hx;

        // ---- publish: transpose through LDS, then contiguous 32B-per-b rows
        if (kg < 16) tbuf[kg * 9 + j] = hn;   // kg == b for kg<16
        __syncthreads();
        float* dst = hbuf + (size_t)(g * 2 + (t & 1)) * (BG * H_Q);
        if (tid < BG * JW) {
            int b = tid >> 3, jl = tid & 7;
            __hip_atomic_store(dst + b * H_Q + s * JW + jl, tbuf[b * 9 + jl],
                               __ATOMIC_RELAXED, __HIP_MEMORY_SCOPE_AGENT);
        }
        asm volatile("s_waitcnt vmcnt(0)" ::: "memory");
        __syncthreads();
        if (tid == 0)
            __hip_atomic_store(flags + wg, t, __ATOMIC_RELAXED, __HIP_MEMORY_SCOPE_AGENT);

        lr = rg; lz = zg; ln = ng; lh = hn;
    }

    // ---- all-done barrier: every WG published step T -> no hbuf readers left
    {
        int cnt = 0;
        while (__hip_atomic_load(flags + tid, __ATOMIC_RELAXED,
                                 __HIP_MEMORY_SCOPE_AGENT) < T_Q ||
               __hip_atomic_load(flags + tid + 256, __ATOMIC_RELAXED,
                                 __HIP_MEMORY_SCOPE_AGENT) < T_Q) {
            __builtin_amdgcn_s_sleep(2);
            if (++cnt > 100000000) break;   // hang guard
        }
    }
    __syncthreads();

    if (kg < 16) {
        size_t o = (size_t)(g * BG + kg) * (4 * H_Q);
        out[o + jg]             = lr;
        out[o + H_Q + jg]       = lz;
        out[o + 2 * H_Q + jg]   = ln;
        out[o + 3 * H_Q + jg]   = lh;
        size_t o2 = o + (size_t)B_Q * (4 * H_Q);
        out[o2 + jg]            = lr;
        out[o2 + H_Q + jg]      = lz;
        out[o2 + 2 * H_Q + jg]  = ln;
        out[o2 + 3 * H_Q + jg]  = lh;
    }
}

extern "C" void kernel_launch(void* const* d_in, const int* in_sizes, int n_in,
                              void* d_out, int out_size, void* d_ws, size_t ws_size,
                              hipStream_t stream) {
    const float* x   = (const float*)d_in[0];
    const float* h0  = (const float*)d_in[1];
    const float* Wih = (const float*)d_in[2];
    const float* bih = (const float*)d_in[3];
    const float* Whh = (const float*)d_in[4];
    const float* bhh = (const float*)d_in[5];
    float* outp  = (float*)d_out;
    int*   flags = (int*)d_ws;   // 2 KB; poison 0xAA (<1) is a valid init

    (void)in_sizes; (void)n_in; (void)ws_size; (void)out_size;

    gru_scan_kernel<<<dim3(NWG), dim3(NTHR), LDS_BYTES, stream>>>(
        x, h0, Wih, bih, Whh, bhh, outp, flags);
}